// Round 12
// baseline (436.229 us; speedup 1.0000x reference)
//
#include <hip/hip_runtime.h>
#include <hip/hip_bf16.h>
#include <math.h>

// ---------------------------------------------------------------------------
// Round 21. R20: glu 8-phase WORKED (443.3 -> 422.8). Leader: attn 87us.
// Changes:
//  1) attn: tile-ready __syncthreads (which drains vmcnt(0), killing the
//     T14 prefetch) -> lgkmcnt(0)-only raw barrier; K/V loads for kt+1
//     now fly across kt's whole compute. + T5 setprio around MFMA
//     clusters (m191: +4-7% attn).
//  2) proj & w3 ported from 2-phase 128^2 to 8-phase 256x128 (mgemm8):
//     grid (8,32)=256 blocks=1/CU, LDS 96KB, acc[8][2]; vmcnt(2)
//     boundary bookkeeping identical to R19's hazard-verified schedule
//     (every boundary follows a 2-load stA). Old 2-phase mgemm removed.
// qkv / glu (8-phase) / cvt_all unchanged (R20-proven).
// ---------------------------------------------------------------------------

#define SEQ     2048
#define BATCH   4
#define NH      16
#define CDIM    1024
#define MROWS   8192

typedef __bf16 bf16x8 __attribute__((ext_vector_type(8)));
typedef float  floatx4 __attribute__((ext_vector_type(4)));
typedef float  floatx16 __attribute__((ext_vector_type(16)));
typedef unsigned int u32;

__device__ __forceinline__ unsigned short f2bf(float f) {
    __bf16 h = (__bf16)f;                      // RNE, HW cvt on gfx950
    return __builtin_bit_cast(unsigned short, h);
}
__device__ __forceinline__ float fexp2(float x) {   // 2^x
    float r; asm("v_exp_f32 %0, %1" : "=v"(r) : "v"(x)); return r;
}
__device__ __forceinline__ float frcp(float x) {    // ~1ulp 1/x
    float r; asm("v_rcp_f32 %0, %1" : "=v"(r) : "v"(x)); return r;
}
__device__ __forceinline__ u32 cvtpk(float lo, float hi) {  // 2xbf16 word
    u32 w; asm("v_cvt_pk_bf16_f32 %0, %1, %2" : "=v"(w) : "v"(lo), "v"(hi));
    return w;
}
__device__ __forceinline__ floatx4 mfma16(bf16x8 a, bf16x8 b, floatx4 c) {
    return __builtin_amdgcn_mfma_f32_16x16x32_bf16(a, b, c, 0, 0, 0);
}
__device__ __forceinline__ floatx16 mfma32(bf16x8 a, bf16x8 b, floatx16 c) {
    return __builtin_amdgcn_mfma_f32_32x32x16_bf16(a, b, c, 0, 0, 0);
}
// async global->LDS, 16B/lane; LDS dest wave-uniform base + lane*16
__device__ __forceinline__ void gld16(void* lds, const void* g) {
    __builtin_amdgcn_global_load_lds(
        (const __attribute__((address_space(1))) u32*)g,
        (__attribute__((address_space(3))) u32*)lds, 16, 0, 0);
}

// ============================================================
// Shared 8-phase machinery (T3+T4+T5). RD_A/RD_B/DO_MFMA are
// redefined per kernel family; the loop macro expands at use site.
// ============================================================
#define PH_ENTER()                                                        \
    __builtin_amdgcn_s_barrier();                                         \
    asm volatile("s_waitcnt lgkmcnt(0)" ::: "memory");                    \
    __builtin_amdgcn_sched_barrier(0);                                    \
    __builtin_amdgcn_s_setprio(1)

#define PH_EXIT() __builtin_amdgcn_s_setprio(0)

// 8-phase main loop (NJ iters x 2 K-tiles x BK=64). Every boundary
// follows a 2-load stA -> vmcnt(2) leaves exactly that stage in flight.
#define EIGHT_PHASE_LOOP(NJ)                                              \
    stA(0, 0, 0); stA(0, 1, 0); stB(0, 0, 0); stB(0, 1, 0);               \
    stA(1, 0, 64);                                                        \
    asm volatile("s_waitcnt vmcnt(2)" ::: "memory");                      \
    __builtin_amdgcn_s_barrier();                                         \
    __builtin_amdgcn_sched_barrier(0);                                    \
    for (int j = 0; j < (NJ); ++j) {                                      \
        const int k1 = (2 * j + 1) * 64;                                  \
        const int k2 = (2 * j + 2) * 64;                                  \
        const int k3 = (2 * j + 3) * 64;                                  \
        const bool more = (j < (NJ) - 1);                                 \
        RD_A(0, 0); RD_B(0, 0);                                           \
        stA(1, 1, k1);                                                    \
        PH_ENTER(); DO_MFMA(0, 0); PH_EXIT();                             \
        __builtin_amdgcn_s_barrier();                                     \
        RD_B(0, 1);                                                       \
        stB(1, 0, k1);                                                    \
        PH_ENTER(); DO_MFMA(0, 1); PH_EXIT();                             \
        __builtin_amdgcn_s_barrier();                                     \
        RD_A(0, 1);                                                       \
        stB(1, 1, k1);                                                    \
        PH_ENTER(); DO_MFMA(1, 1); PH_EXIT();                             \
        __builtin_amdgcn_s_barrier();                                     \
        if (more) stA(0, 0, k2);                                          \
        PH_ENTER(); DO_MFMA(1, 0); PH_EXIT();                             \
        if (more) { asm volatile("s_waitcnt vmcnt(2)" ::: "memory"); }    \
        else      { asm volatile("s_waitcnt vmcnt(0)" ::: "memory"); }    \
        __builtin_amdgcn_s_barrier();                                     \
        RD_A(1, 0); RD_B(1, 0);                                           \
        if (more) stA(0, 1, k2);                                          \
        PH_ENTER(); DO_MFMA(0, 0); PH_EXIT();                             \
        __builtin_amdgcn_s_barrier();                                     \
        RD_B(1, 1);                                                       \
        if (more) stB(0, 0, k2);                                          \
        PH_ENTER(); DO_MFMA(0, 1); PH_EXIT();                             \
        __builtin_amdgcn_s_barrier();                                     \
        RD_A(1, 1);                                                       \
        if (more) stB(0, 1, k2);                                          \
        PH_ENTER(); DO_MFMA(1, 1); PH_EXIT();                             \
        __builtin_amdgcn_s_barrier();                                     \
        if (more) stA(1, 0, k3);                                          \
        PH_ENTER(); DO_MFMA(1, 0); PH_EXIT();                             \
        if (more) {                                                       \
            asm volatile("s_waitcnt vmcnt(2)" ::: "memory");              \
            __builtin_amdgcn_s_barrier();                                 \
        }                                                                 \
    }

// ---- variant V16: 256x256 tile, 8 waves 2Mx4N, acc[8][4] ----
#define RD_A(buf, mh)                                                     \
    { _Pragma("unroll") for (int i_ = 0; i_ < 4; ++i_) {                  \
        const int ro_ = (arow + ((mh) * 4 + i_) * 16) * 64;               \
        aF[i_][0] = *(const bf16x8*)&As[buf][ro_ + e0];                   \
        aF[i_][1] = *(const bf16x8*)&As[buf][ro_ + e1]; } }

#define RD_B(buf, nh)                                                     \
    { _Pragma("unroll") for (int n_ = 0; n_ < 2; ++n_) {                  \
        const int ro_ = (brow + ((nh) * 2 + n_) * 16) * 64;               \
        bF[nh][n_][0] = *(const bf16x8*)&Bs[buf][ro_ + e0];               \
        bF[nh][n_][1] = *(const bf16x8*)&Bs[buf][ro_ + e1]; } }

#define DO_MFMA(mh, nh)                                                   \
    { _Pragma("unroll") for (int i_ = 0; i_ < 4; ++i_)                    \
      { _Pragma("unroll") for (int n_ = 0; n_ < 2; ++n_) {                \
        acc[(mh)*4+i_][(nh)*2+n_] =                                       \
            mfma16(aF[i_][0], bF[nh][n_][0], acc[(mh)*4+i_][(nh)*2+n_]);  \
        acc[(mh)*4+i_][(nh)*2+n_] =                                       \
            mfma16(aF[i_][1], bF[nh][n_][1], acc[(mh)*4+i_][(nh)*2+n_]);  \
      } } }

// ============================================================
// Fused SwiGLU GEMM — 8-phase 256^2, 32-row-interleaved B (R20-PROVEN)
// ============================================================
__global__ __launch_bounds__(512, 2) void mgemm_glu(
    const unsigned short* __restrict__ B1p,
    const unsigned short* __restrict__ B2p,
    const unsigned short* __restrict__ A,
    const float* __restrict__ bias1,
    const float* __restrict__ bias2,
    unsigned short* __restrict__ C, int ldc)
{
    __shared__ __align__(16) unsigned short As[2][256 * 64];
    __shared__ __align__(16) unsigned short Bs[2][256 * 64];

    const int tid  = threadIdx.x;
    const int lane = tid & 63;
    const int wave = tid >> 6;          // 0..7
    const int l16  = lane & 15;
    const int quad = lane >> 4;
    const int wr   = wave >> 2;         // M half (0..1)
    const int wc   = wave & 3;          // N quarter (0..3)
    const int bn = blockIdx.x, bm = blockIdx.y;
    const int K = CDIM;

    const unsigned short* Ag = A + (size_t)(bm * 256) * K;

    const int srow  = lane >> 3;
    const int sgcol = ((lane & 7) ^ srow) * 8;

    auto stA = [&](int buf, int half, int kt) {
        #pragma unroll
        for (int s = 0; s < 2; ++s) {
            const int rbase = half * 128 + (wave * 2 + s) * 8;
            gld16(&As[buf][rbase * 64],
                  Ag + (size_t)(rbase + srow) * K + kt + sgcol);
        }
    };
    // interleaved B: LDS row rho -> q=rho>>6, r6=rho&63;
    // r6<32 -> W1 row bn*128+q*32+r6 ; else W2 row bn*128+q*32+(r6-32)
    auto stB = [&](int buf, int half, int kt) {
        #pragma unroll
        for (int s = 0; s < 2; ++s) {
            const int rbase = half * 128 + (wave * 2 + s) * 8;
            const int q = rbase >> 6, r6 = rbase & 63;
            const unsigned short* src = (r6 < 32)
                ? B1p + (size_t)(bn * 128 + q * 32 + r6) * K
                : B2p + (size_t)(bn * 128 + q * 32 + (r6 - 32)) * K;
            gld16(&Bs[buf][rbase * 64],
                  src + (size_t)srow * K + kt + sgcol);
        }
    };

    const int e0 = ((quad)     ^ (l16 & 7)) * 8;
    const int e1 = ((quad + 4) ^ (l16 & 7)) * 8;
    const int arow = wr * 128 + l16;
    const int brow = wc * 64 + l16;

    floatx4 acc[8][4] = {};
    bf16x8 aF[4][2];
    bf16x8 bF[2][2][2];

    EIGHT_PHASE_LOOP(8);

    // epilogue: intra-wave GLU combine, fast silu
    #pragma unroll
    for (int nt = 0; nt < 2; ++nt) {
        const int gcol = bn * 128 + wc * 32 + nt * 16 + l16;
        const float b1 = bias1[gcol];
        const float b2 = bias2[gcol];
        #pragma unroll
        for (int m = 0; m < 8; ++m) {
            #pragma unroll
            for (int r = 0; r < 4; ++r) {
                const int grow = bm * 256 + wr * 128 + m * 16 + quad * 4 + r;
                const float x1 = acc[m][nt][r] + b1;
                const float x2 = acc[m][nt + 2][r] + b2;
                const float e = fexp2(x1 * -1.44269504088896f);
                const float v = x1 * frcp(1.0f + e) * x2;
                C[(size_t)grow * ldc + gcol] = f2bf(v);
            }
        }
    }
}

// ============================================================
// QKV GEMM — 8-phase 256^2 (R19-PROVEN, unchanged)
// ============================================================
__global__ __launch_bounds__(512, 2) void mgemm_qkv(
    const unsigned short* __restrict__ A,
    const unsigned short* __restrict__ B,
    const float* __restrict__ tab,
    unsigned short* __restrict__ Qb,
    unsigned short* __restrict__ Kb,
    unsigned short* __restrict__ Vtb)
{
    __shared__ __align__(16) unsigned short As[2][256 * 64];
    __shared__ __align__(16) unsigned short Bs[2][256 * 64];

    const int tid  = threadIdx.x;
    const int lane = tid & 63;
    const int wave = tid >> 6;          // 0..7
    const int l16  = lane & 15;
    const int quad = lane >> 4;
    const int wr   = wave >> 2;         // M half (0..1)
    const int wc   = wave & 3;          // N quarter (0..3)
    const int bn = blockIdx.x, bm = blockIdx.y;
    const int K = CDIM;

    const unsigned short* Ag = A + (size_t)(bm * 256) * K;
    const unsigned short* Bg = B + (size_t)(bn * 256) * K;

    const int srow  = lane >> 3;
    const int sgcol = ((lane & 7) ^ srow) * 8;

    auto stA = [&](int buf, int half, int kt) {
        #pragma unroll
        for (int s = 0; s < 2; ++s) {
            const int rbase = half * 128 + (wave * 2 + s) * 8;
            gld16(&As[buf][rbase * 64],
                  Ag + (size_t)(rbase + srow) * K + kt + sgcol);
        }
    };
    auto stB = [&](int buf, int half, int kt) {
        #pragma unroll
        for (int s = 0; s < 2; ++s) {
            const int rbase = half * 128 + (wave * 2 + s) * 8;
            gld16(&Bs[buf][rbase * 64],
                  Bg + (size_t)(rbase + srow) * K + kt + sgcol);
        }
    };

    const int e0 = ((quad)     ^ (l16 & 7)) * 8;
    const int e1 = ((quad + 4) ^ (l16 & 7)) * 8;
    const int arow = wr * 128 + l16;
    const int brow = wc * 64 + l16;

    floatx4 acc[8][4] = {};
    bf16x8 aF[4][2];
    bf16x8 bF[2][2][2];

    EIGHT_PHASE_LOOP(8);

    // ---- epilogues ----
    const int part = bn >> 2;           // 0=q 1=k 2=v (256-col blocks)

    if (part == 2) {
        // V: transpose via LDS (As dead) -> Vtb [bh][d][n], 32B stores
        unsigned short* T = &As[0][0];  // [2][256][16] ushort = 16 KB
        #pragma unroll
        for (int m = 0; m < 8; ++m) {
            __syncthreads();
            #pragma unroll
            for (int n = 0; n < 4; ++n) {
                ushort4 pk;
                pk.x = f2bf(acc[m][n][0]); pk.y = f2bf(acc[m][n][1]);
                pk.z = f2bf(acc[m][n][2]); pk.w = f2bf(acc[m][n][3]);
                *(ushort4*)&T[(wr * 256 + wc * 64 + n * 16 + l16) * 16 + quad * 4] = pk;
            }
            __syncthreads();
            // 512 threads: wr2 = tid>>8, col = tid&255; 32B along n
            const int wr2 = tid >> 8, col = tid & 255;
            const int grow0 = bm * 256 + wr2 * 128 + m * 16;
            const int b = grow0 >> 11, n0 = grow0 & 2047;
            const int h2 = (bn & 3) * 4 + (col >> 6);
            const int d  = col & 63;
            unsigned short* dst = Vtb +
                ((size_t)(b * NH + h2) * 64 + d) * 2048 + n0;
            const int tb = (wr2 * 256 + col) * 16;
            *(uint4*)dst       = *(const uint4*)&T[tb];
            *(uint4*)(dst + 8) = *(const uint4*)&T[tb + 8];
        }
    } else {
        // q/k: fp32 RoPE; q scaled by 0.125*log2e (exp2 softmax)
        const float qscale = (part == 0) ? 0.125f * 1.44269504088896f : 1.0f;
        const int h = (bn & 3) * 4 + wc;
        unsigned short* qk = (part == 0) ? Qb : Kb;
        #pragma unroll
        for (int m = 0; m < 8; ++m) {
            #pragma unroll
            for (int r = 0; r < 4; ++r) {
                const int grow = bm * 256 + wr * 128 + m * 16 + quad * 4 + r;
                const int b = grow >> 11, n = grow & 2047;
                unsigned short* dst = qk + ((size_t)(b * NH + h) * 2048 + n) * 64;
                #pragma unroll
                for (int nt = 0; nt < 2; ++nt) {
                    const int i = nt * 16 + l16;          // 0..31
                    const float c  = tab[(n * 32 + i) * 2];
                    const float sn = tab[(n * 32 + i) * 2 + 1];
                    const float x1  = acc[m][nt][r];
                    const float x2v = acc[m][nt + 2][r];
                    dst[i]      = f2bf((x1 * c - x2v * sn) * qscale);
                    dst[i + 32] = f2bf((x2v * c + x1 * sn) * qscale);
                }
            }
        }
    }
}

// ---- variant V8: 256x128 tile, 8 waves 2Mx4N (per-wave 128x32) ----
#undef RD_B
#undef DO_MFMA
#define RD_B(buf, nh)                                                     \
    { const int ro_ = (brow + (nh) * 16) * 64;                            \
      bF[nh][0] = *(const bf16x8*)&Bs[buf][ro_ + e0];                     \
      bF[nh][1] = *(const bf16x8*)&Bs[buf][ro_ + e1]; }

#define DO_MFMA(mh, nh)                                                   \
    { _Pragma("unroll") for (int i_ = 0; i_ < 4; ++i_) {                  \
        acc[(mh)*4+i_][nh] =                                              \
            mfma16(aF[i_][0], bF[nh][0], acc[(mh)*4+i_][nh]);             \
        acc[(mh)*4+i_][nh] =                                              \
            mfma16(aF[i_][1], bF[nh][1], acc[(mh)*4+i_][nh]); } }

// ============================================================
// mgemm8: bf16 MFMA GEMM NT, 8-phase 256x128 tile:
// C[m,n] = sum_k A[m,k]*B[n,k] (+bias). Grid (N/128, M/256), 512 thr.
// LDS 96KB (A 2x32KB + B 2x16KB); acc[8][2].
// ============================================================
template <int OUTMODE, bool BIAS>
__global__ __launch_bounds__(512, 2) void mgemm8(
    const unsigned short* __restrict__ A,
    const unsigned short* __restrict__ B,
    const float* __restrict__ bias,
    void* __restrict__ C, int ldc,
    int K)
{
    __shared__ __align__(16) unsigned short As[2][256 * 64];
    __shared__ __align__(16) unsigned short Bs[2][128 * 64];

    const int tid  = threadIdx.x;
    const int lane = tid & 63;
    const int wave = tid >> 6;          // 0..7
    const int l16  = lane & 15;
    const int quad = lane >> 4;
    const int wr   = wave >> 2;         // M half (0..1)
    const int wc   = wave & 3;          // N quarter (0..3), 32 cols each
    const int bn = blockIdx.x, bm = blockIdx.y;

    const unsigned short* Ag = A + (size_t)(bm * 256) * K;
    const unsigned short* Bg = B + (size_t)(bn * 128) * K;

    const int srow  = lane >> 3;
    const int sgcol = ((lane & 7) ^ srow) * 8;

    auto stA = [&](int buf, int half, int kt) {      // 2 gld16 (128 rows/half)
        #pragma unroll
        for (int s = 0; s < 2; ++s) {
            const int rbase = half * 128 + (wave * 2 + s) * 8;
            gld16(&As[buf][rbase * 64],
                  Ag + (size_t)(rbase + srow) * K + kt + sgcol);
        }
    };
    auto stB = [&](int buf, int half, int kt) {      // 1 gld16 (64 rows/half)
        const int rbase = half * 64 + wave * 8;
        gld16(&Bs[buf][rbase * 64],
              Bg + (size_t)(rbase + srow) * K + kt + sgcol);
    };

    const int e0 = ((quad)     ^ (l16 & 7)) * 8;
    const int e1 = ((quad + 4) ^ (l16 & 7)) * 8;
    const int arow = wr * 128 + l16;
    const int brow = wc * 32 + l16;

    floatx4 acc[8][2] = {};
    bf16x8 aF[4][2];
    bf16x8 bF[2][2];

    const int NJ = K >> 7;
    EIGHT_PHASE_LOOP(NJ);

    #pragma unroll
    for (int nt = 0; nt < 2; ++nt) {
        const int gcol = bn * 128 + wc * 32 + nt * 16 + l16;
        const float bv = BIAS ? bias[gcol] : 0.0f;
        #pragma unroll
        for (int m = 0; m < 8; ++m) {
            #pragma unroll
            for (int r = 0; r < 4; ++r) {
                const int grow = bm * 256 + wr * 128 + m * 16 + quad * 4 + r;
                float v = acc[m][nt][r] + bv;
                if (OUTMODE == 0)
                    ((float*)C)[(size_t)grow * ldc + gcol] = v;
                else
                    ((unsigned short*)C)[(size_t)grow * ldc + gcol] = f2bf(v);
            }
        }
    }
}

// ============================================================
// MFMA flash attention v5: as v4, but the tile-ready barrier is
// lgkmcnt-only (no vmcnt drain) so the T14 K/V prefetch actually
// spans kt's compute; setprio around MFMA clusters (T5).
// ============================================================
__global__ __launch_bounds__(256) void attn_mfma(
    const unsigned short* __restrict__ Qb,
    const unsigned short* __restrict__ Kb,
    const unsigned short* __restrict__ Vtb,
    unsigned short* __restrict__ Ob)
{
    const int bh = blockIdx.x;        // 0..63  (x-major: same-bh -> same XCD)
    const int qt = blockIdx.y;        // 0..15
    const int tid = threadIdx.x;
    const int lane = tid & 63, wave = tid >> 6;
    const int r32 = lane & 31, hi = lane >> 5;
    const int qrow = wave * 32 + r32; // this lane's query row in LDS

    __shared__ unsigned short QP[128][72];  // Q staging (held all iters)
    __shared__ unsigned short Ks[64][72];   // K tile [key][dim]
    __shared__ unsigned short Vs[64][72];   // V^T tile [dim][key]

    const unsigned short* Qg = Qb + ((size_t)bh * 2048 + qt * 128) * 64;
    const unsigned short* Kg = Kb + (size_t)bh * 2048 * 64;
    const unsigned short* Vg = Vtb + (size_t)bh * 64 * 2048;

    // stage Q tile 128x64
    #pragma unroll
    for (int rep = 0; rep < 4; ++rep) {
        const int c = tid + rep * 256;
        const int r = c >> 3, d0 = (c & 7) * 8;
        *(uint4*)&QP[r][d0] = *(const uint4*)(Qg + (size_t)r * 64 + d0);
    }

    // K/V staging slots for this thread (2 b128 each per tile)
    const int c0 = tid, c1 = tid + 256;
    const int kr0 = c0 >> 3, kd0 = (c0 & 7) * 8;
    const int kr1 = c1 >> 3, kd1 = (c1 & 7) * 8;

    // T14 prefetch tile 0 into regs
    uint4 ka0 = *(const uint4*)(Kg + (size_t)kr0 * 64 + kd0);
    uint4 ka1 = *(const uint4*)(Kg + (size_t)kr1 * 64 + kd1);
    uint4 va0 = *(const uint4*)(Vg + (size_t)kr0 * 2048 + kd0);
    uint4 va1 = *(const uint4*)(Vg + (size_t)kr1 * 2048 + kd1);

    __syncthreads();   // Q tile ready

    // Q B-frags (rows = wave's 32 queries), held for all iterations
    bf16x8 bq[4];
    #pragma unroll
    for (int f = 0; f < 4; ++f)
        bq[f] = *(const bf16x8*)&QP[qrow][f * 16 + hi * 8];

    floatx16 o0 = {}, o1 = {};      // O^T[d][q]: d-tiles 0..31 / 32..63
    float l_acc = 0.0f;

    for (int kt = 0; kt < 32; ++kt) {
        __syncthreads();   // prev tile's Ks/Vs frag reads complete
        *(uint4*)&Ks[kr0][kd0] = ka0;
        *(uint4*)&Ks[kr1][kd1] = ka1;
        *(uint4*)&Vs[kr0][kd0] = va0;
        *(uint4*)&Vs[kr1][kd1] = va1;
        if (kt + 1 < 32) {           // T14: issue next-tile loads now;
            const size_t nb = (size_t)(kt + 1) * 64;     // they stay in flight
            ka0 = *(const uint4*)(Kg + (nb + kr0) * 64 + kd0);   // across kt's
            ka1 = *(const uint4*)(Kg + (nb + kr1) * 64 + kd1);   // compute (no
            va0 = *(const uint4*)(Vg + (size_t)kr0 * 2048 + nb + kd0); // vmcnt
            va1 = *(const uint4*)(Vg + (size_t)kr1 * 2048 + nb + kd1); // drain)
        }
        // tile-ready: ds_writes visible; do NOT drain vmcnt (prefetch flies)
        asm volatile("s_waitcnt lgkmcnt(0)" ::: "memory");
        __builtin_amdgcn_s_barrier();
        __builtin_amdgcn_sched_barrier(0);

        // ---- per 32-key subtile: S^T -> exp2 -> in-reg P -> PV ----
        #pragma unroll
        for (int t = 0; t < 2; ++t) {
            floatx16 s = {};
            __builtin_amdgcn_s_setprio(1);
            #pragma unroll
            for (int f = 0; f < 4; ++f) {
                const bf16x8 ak = *(const bf16x8*)&Ks[t * 32 + r32][f * 16 + hi * 8];
                s = mfma32(ak, bq[f], s);
            }
            __builtin_amdgcn_s_setprio(0);
            // p = exp2(s); rowsum
            float p[16];
            float rs = 0.0f;
            #pragma unroll
            for (int g = 0; g < 16; ++g) { p[g] = fexp2(s[g]); rs += p[g]; }
            l_acc += rs;
            // pack to bf16 words and swap halves across hi
            u32 w0 = cvtpk(p[0], p[1]),   w2 = cvtpk(p[4], p[5]);
            u32 w1 = cvtpk(p[2], p[3]),   w3 = cvtpk(p[6], p[7]);
            u32 w4 = cvtpk(p[8], p[9]),   w6 = cvtpk(p[12], p[13]);
            u32 w5 = cvtpk(p[10], p[11]), w7 = cvtpk(p[14], p[15]);
            asm("v_permlane32_swap_b32 %0, %1" : "+v"(w0), "+v"(w2));
            asm("v_permlane32_swap_b32 %0, %1" : "+v"(w1), "+v"(w3));
            asm("v_permlane32_swap_b32 %0, %1" : "+v"(w4), "+v"(w6));
            asm("v_permlane32_swap_b32 %0, %1" : "+v"(w5), "+v"(w7));
            uint4 u0; u0.x = w0; u0.y = w1; u0.z = w2; u0.w = w3;
            uint4 u1; u1.x = w4; u1.y = w5; u1.z = w6; u1.w = w7;
            const bf16x8 bp0 = __builtin_bit_cast(bf16x8, u0);  // keys t*32 + slot0
            const bf16x8 bp1 = __builtin_bit_cast(bf16x8, u1);  // keys t*32 + slot1
            // PV for this subtile's two 16-key slots (f = 2t, 2t+1)
            {
                const int f0 = 2 * t, f1 = 2 * t + 1;
                const bf16x8 av00 = *(const bf16x8*)&Vs[r32][f0 * 16 + hi * 8];
                const bf16x8 av01 = *(const bf16x8*)&Vs[32 + r32][f0 * 16 + hi * 8];
                __builtin_amdgcn_s_setprio(1);
                o0 = mfma32(av00, bp0, o0);
                o1 = mfma32(av01, bp0, o1);
                __builtin_amdgcn_s_setprio(0);
                const bf16x8 av10 = *(const bf16x8*)&Vs[r32][f1 * 16 + hi * 8];
                const bf16x8 av11 = *(const bf16x8*)&Vs[32 + r32][f1 * 16 + hi * 8];
                __builtin_amdgcn_s_setprio(1);
                o0 = mfma32(av10, bp1, o0);
                o1 = mfma32(av11, bp1, o1);
                __builtin_amdgcn_s_setprio(0);
            }
        }
    }

    // epilogue: lane's query = wave*32 + r32; lanes l/l+32 hold disjoint key
    // halves of the same query -> one shfl to complete l.
    const float l_tot = l_acc + __shfl_xor(l_acc, 32);
    const float inv = 1.0f / l_tot;
    const int b = bh >> 4, h = bh & 15;
    unsigned short* orow = Ob +
        (size_t)(b * SEQ + qt * 128 + qrow) * CDIM + h * 64;
    #pragma unroll
    for (int u = 0; u < 2; ++u) {
        const floatx16 ov = u ? o1 : o0;
        #pragma unroll
        for (int g = 0; g < 4; ++g) {
            ushort4 pk;
            pk.x = f2bf(ov[4 * g + 0] * inv); pk.y = f2bf(ov[4 * g + 1] * inv);
            pk.z = f2bf(ov[4 * g + 2] * inv); pk.w = f2bf(ov[4 * g + 3] * inv);
            // d = u*32 + 8g + 4*hi + (0..3)
            *(ushort4*)(orow + u * 32 + 8 * g + 4 * hi) = pk;
        }
    }
}

// ============================================================
// One-shot fp32 -> bf16 for all six tensors (block-uniform segments);
// RoPE table (fp64 angles)
// ============================================================
__global__ __launch_bounds__(256) void cvt_all(
    const float* __restrict__ x,    const float* __restrict__ qkv,
    const float* __restrict__ proj, const float* __restrict__ w1,
    const float* __restrict__ w2,   const float* __restrict__ w3,
    unsigned short* __restrict__ xb,    unsigned short* __restrict__ qkvb,
    unsigned short* __restrict__ projb, unsigned short* __restrict__ w1b,
    unsigned short* __restrict__ w2b,   unsigned short* __restrict__ w3b)
{
    const size_t i = ((size_t)blockIdx.x * 256 + threadIdx.x) * 4;
    const float* src; unsigned short* dst; size_t off;
    if      (i <  8388608) { src = x;    dst = xb;    off = 0; }
    else if (i < 11534336) { src = qkv;  dst = qkvb;  off = 8388608; }
    else if (i < 12582912) { src = proj; dst = projb; off = 11534336; }
    else if (i < 14680064) { src = w1;   dst = w1b;   off = 12582912; }
    else if (i < 16777216) { src = w2;   dst = w2b;   off = 14680064; }
    else                   { src = w3;   dst = w3b;   off = 16777216; }
    const size_t j = i - off;
    const float4 f = *(const float4*)(src + j);
    ushort4 o; o.x = f2bf(f.x); o.y = f2bf(f.y); o.z = f2bf(f.z); o.w = f2bf(f.w);
    *(ushort4*)(dst + j) = o;
}

__global__ __launch_bounds__(256) void rope_table(float* __restrict__ tab)
{
    const int idx = blockIdx.x * 256 + threadIdx.x;   // < 65536
    const int i = idx & 31, n = idx >> 5;
    const double f = (double)n * pow(10000.0, -(double)(2 * i) / 64.0);
    tab[idx * 2]     = (float)cos(f);
    tab[idx * 2 + 1] = (float)sin(f);
}

// ============================================================
// kernel_launch
// ============================================================
extern "C" void kernel_launch(void* const* d_in, const int* in_sizes, int n_in,
                              void* d_out, int out_size, void* d_ws, size_t ws_size,
                              hipStream_t stream)
{
    const float* x      = (const float*)d_in[0];
    const float* qkv_w  = (const float*)d_in[1];
    const float* proj_w = (const float*)d_in[2];
    const float* proj_b = (const float*)d_in[3];
    const float* w1_w   = (const float*)d_in[4];
    const float* w1_b   = (const float*)d_in[5];
    const float* w2_w   = (const float*)d_in[6];
    const float* w2_b   = (const float*)d_in[7];
    const float* w3_w   = (const float*)d_in[8];
    const float* w3_b   = (const float*)d_in[9];
    float* out = (float*)d_out;

    char* ws = (char*)d_ws;
    unsigned short* Qb    = (unsigned short*)(ws);              // [0,16M)
    unsigned short* Kb    = (unsigned short*)(ws + 16777216);   // [16,32M)
    unsigned short* Vtb   = (unsigned short*)(ws + 33554432);   // [32,48M)
    unsigned short* Ob    = (unsigned short*)(ws + 50331648);   // [48,64M)
    unsigned short* out1b = (unsigned short*)(ws + 67108864);   // [64,80M)
    unsigned short* w1b   = (unsigned short*)(ws + 83886080);   // [80,84M)
    unsigned short* w2b   = (unsigned short*)(ws + 88080384);   // [84,88M)
    unsigned short* w3b   = (unsigned short*)(ws + 92274688);   // [88,92M)
    unsigned short* projb = (unsigned short*)(ws + 96468992);   // [92,94M)
    unsigned short* xb    = (unsigned short*)(ws + 98566144);   // [94,110M)
    unsigned short* wqkvb = (unsigned short*)(ws + 115343360);  // [110,116M)
    float*          tab   = (float*)(ws + 121634816);           // [116,116.5M)
    unsigned short* hid   = (unsigned short*)(ws);              // [0,32M)

    const dim3 blk(256);

    // all fp32->bf16 conversions in one dispatch (18874368 elems / 1024)
    cvt_all<<<dim3(18432), blk, 0, stream>>>(
        x, qkv_w, proj_w, w1_w, w2_w, w3_w,
        xb, wqkvb, projb, w1b, w2b, w3b);
    rope_table<<<dim3(256), blk, 0, stream>>>(tab);

    // 1) QKV GEMM (8-phase 256^2) + fused rope/scale + V transpose
    mgemm_qkv<<<dim3(12, 32), dim3(512), 0, stream>>>(xb, wqkvb, tab, Qb, Kb, Vtb);
    // 2) MFMA flash attention; grid (bh, qt) -> same-bh blocks co-XCD
    attn_mfma<<<dim3(BATCH * NH, SEQ / 128), blk, 0, stream>>>(Qb, Kb, Vtb, Ob);
    // 3) out1b = Ob @ projb^T + proj_b (bf16)  [8-phase 256x128]
    mgemm8<1, true><<<dim3(8, 32), dim3(512), 0, stream>>>(
        Ob, projb, proj_b, out1b, CDIM, CDIM);
    // 4) hid = silu(out1b@w1^T + b1) * (out1b@w2^T + b2)  [8-phase fused]
    mgemm_glu<<<dim3(16, 32), dim3(512), 0, stream>>>(
        w1b, w2b, out1b, w1_b, w2_b, hid, 2048);
    // 5) out = hid @ w3b^T + w3_b (fp32 -> d_out)  [8-phase 256x128]
    mgemm8<0, true><<<dim3(8, 32), dim3(512), 0, stream>>>(
        hid, w3b, w3_b, out, CDIM, 2048);
}

// Round 13
// 425.297 us; speedup vs baseline: 1.0257x; 1.0257x over previous
//
#include <hip/hip_runtime.h>
#include <hip/hip_bf16.h>
#include <math.h>

// ---------------------------------------------------------------------------
// Round 22. R21 regressed (436.2 vs R20's 422.8) and BUNDLED three deltas
// (attn lgkm-barrier + attn setprio + proj/w3 mgemm8). Decomposed: attn
// +7.5us (likely setprio: m190 measured it NEGATIVE on barrier-synced
// lockstep waves, which attn's 4-wave block is); proj/w3 mgemm8 ~+6us
// (1 block/CU occupancy). Un-bundle:
//  - attn: KEEP lgkm-only tile-ready barrier (prefetch spans compute;
//    mechanism sound), REMOVE all setprio. Single delta vs R20.
//  - proj/w3: reverted to R20-proven 2-phase mgemm.
// Pre-commit: attn<=85 -> setprio was culprit; attn~94 -> revert barrier.
// qkv / glu (8-phase) / cvt_all unchanged (R20-proven).
// ---------------------------------------------------------------------------

#define SEQ     2048
#define BATCH   4
#define NH      16
#define CDIM    1024
#define MROWS   8192

typedef __bf16 bf16x8 __attribute__((ext_vector_type(8)));
typedef float  floatx4 __attribute__((ext_vector_type(4)));
typedef float  floatx16 __attribute__((ext_vector_type(16)));
typedef unsigned int u32;

__device__ __forceinline__ unsigned short f2bf(float f) {
    __bf16 h = (__bf16)f;                      // RNE, HW cvt on gfx950
    return __builtin_bit_cast(unsigned short, h);
}
__device__ __forceinline__ float fexp2(float x) {   // 2^x
    float r; asm("v_exp_f32 %0, %1" : "=v"(r) : "v"(x)); return r;
}
__device__ __forceinline__ float frcp(float x) {    // ~1ulp 1/x
    float r; asm("v_rcp_f32 %0, %1" : "=v"(r) : "v"(x)); return r;
}
__device__ __forceinline__ u32 cvtpk(float lo, float hi) {  // 2xbf16 word
    u32 w; asm("v_cvt_pk_bf16_f32 %0, %1, %2" : "=v"(w) : "v"(lo), "v"(hi));
    return w;
}
__device__ __forceinline__ floatx4 mfma16(bf16x8 a, bf16x8 b, floatx4 c) {
    return __builtin_amdgcn_mfma_f32_16x16x32_bf16(a, b, c, 0, 0, 0);
}
__device__ __forceinline__ floatx16 mfma32(bf16x8 a, bf16x8 b, floatx16 c) {
    return __builtin_amdgcn_mfma_f32_32x32x16_bf16(a, b, c, 0, 0, 0);
}
// async global->LDS, 16B/lane; LDS dest wave-uniform base + lane*16
__device__ __forceinline__ void gld16(void* lds, const void* g) {
    __builtin_amdgcn_global_load_lds(
        (const __attribute__((address_space(1))) u32*)g,
        (__attribute__((address_space(3))) u32*)lds, 16, 0, 0);
}
// counted-wait + raw barrier (no compiler vmcnt(0) drain at sync)
__device__ __forceinline__ void wait_vm0_barrier() {
    asm volatile("s_waitcnt vmcnt(0)" ::: "memory");
    __builtin_amdgcn_s_barrier();
    __builtin_amdgcn_sched_barrier(0);
}
__device__ __forceinline__ void raw_barrier() {
    __builtin_amdgcn_s_barrier();
    __builtin_amdgcn_sched_barrier(0);
}

// ============================================================
// bf16 MFMA GEMM NT, 2-phase dbuf + slab swizzle (R18/R20-proven):
// C[m,n] = sum_k A[m,k]*B[n,k] (+bias)
// ============================================================
template <int OUTMODE, bool BIAS>
__global__ __launch_bounds__(256) void mgemm(
    const unsigned short* __restrict__ A,
    const unsigned short* __restrict__ B,
    const float* __restrict__ bias,
    void* __restrict__ C, int ldc,
    int K)
{
    __shared__ __align__(16) unsigned short As[2][128 * 32];
    __shared__ __align__(16) unsigned short Bs[2][128 * 32];

    const int tid  = threadIdx.x;
    const int lane = tid & 63;
    const int wave = tid >> 6;
    const int l16  = lane & 15;
    const int quad = lane >> 4;
    const int wm = (wave >> 1) * 64, wn = (wave & 1) * 64;
    const int bm = blockIdx.y, bn = blockIdx.x;

    const unsigned short* Ag = A + (size_t)(bm * 128) * K;
    const unsigned short* Bg = B + (size_t)(bn * 128) * K;

    const int srow0 = wave * 32 + (lane >> 2);
    const int scol  = 8 * ((lane & 3) ^ ((lane >> 3) & 3));
    const unsigned short* gA0 = Ag + (size_t)srow0 * K + scol;
    const unsigned short* gA1 = Ag + (size_t)(srow0 + 16) * K + scol;
    const unsigned short* gB0 = Bg + (size_t)srow0 * K + scol;
    const unsigned short* gB1 = Bg + (size_t)(srow0 + 16) * K + scol;

    auto stage = [&](int b, int kt) {
        gld16(&As[b][(wave * 2 + 0) * 512], gA0 + kt);
        gld16(&As[b][(wave * 2 + 1) * 512], gA1 + kt);
        gld16(&Bs[b][(wave * 2 + 0) * 512], gB0 + kt);
        gld16(&Bs[b][(wave * 2 + 1) * 512], gB1 + kt);
    };

    const int qsw = (quad ^ ((l16 >> 1) & 3)) * 8;

    floatx4 acc[4][4] = {};
    const int NK = K >> 5;

    stage(0, 0);
    wait_vm0_barrier();

    for (int i = 0; i < NK; ++i) {
        const int cur = i & 1;
        if (i + 1 < NK) stage(cur ^ 1, (i + 1) * 32);

        bf16x8 af[4], bfr[4];
        #pragma unroll
        for (int mt = 0; mt < 4; ++mt)
            af[mt] = *(const bf16x8*)&As[cur][(wm + mt * 16 + l16) * 32 + qsw];
        #pragma unroll
        for (int nt = 0; nt < 4; ++nt)
            bfr[nt] = *(const bf16x8*)&Bs[cur][(wn + nt * 16 + l16) * 32 + qsw];
        #pragma unroll
        for (int mt = 0; mt < 4; ++mt)
            #pragma unroll
            for (int nt = 0; nt < 4; ++nt)
                acc[mt][nt] = mfma16(af[mt], bfr[nt], acc[mt][nt]);

        if (i + 1 < NK) wait_vm0_barrier();
        else            raw_barrier();
    }

    #pragma unroll
    for (int nt = 0; nt < 4; ++nt) {
        const int gcol = bn * 128 + wn + nt * 16 + l16;
        const float bv = BIAS ? bias[gcol] : 0.0f;
        #pragma unroll
        for (int mt = 0; mt < 4; ++mt) {
            #pragma unroll
            for (int r = 0; r < 4; ++r) {
                const int grow = bm * 128 + wm + mt * 16 + quad * 4 + r;
                float v = acc[mt][nt][r] + bv;
                if (OUTMODE == 0)
                    ((float*)C)[(size_t)grow * ldc + gcol] = v;
                else
                    ((unsigned short*)C)[(size_t)grow * ldc + gcol] = f2bf(v);
            }
        }
    }
}

// ============================================================
// Shared 8-phase machinery (T3+T4+T5) — 256^2 variant (R19/R20-proven)
// ============================================================
#define RD_A(buf, mh)                                                     \
    { _Pragma("unroll") for (int i_ = 0; i_ < 4; ++i_) {                  \
        const int ro_ = (arow + ((mh) * 4 + i_) * 16) * 64;               \
        aF[i_][0] = *(const bf16x8*)&As[buf][ro_ + e0];                   \
        aF[i_][1] = *(const bf16x8*)&As[buf][ro_ + e1]; } }

#define RD_B(buf, nh)                                                     \
    { _Pragma("unroll") for (int n_ = 0; n_ < 2; ++n_) {                  \
        const int ro_ = (brow + ((nh) * 2 + n_) * 16) * 64;               \
        bF[nh][n_][0] = *(const bf16x8*)&Bs[buf][ro_ + e0];               \
        bF[nh][n_][1] = *(const bf16x8*)&Bs[buf][ro_ + e1]; } }

#define DO_MFMA(mh, nh)                                                   \
    { _Pragma("unroll") for (int i_ = 0; i_ < 4; ++i_)                    \
      { _Pragma("unroll") for (int n_ = 0; n_ < 2; ++n_) {                \
        acc[(mh)*4+i_][(nh)*2+n_] =                                       \
            mfma16(aF[i_][0], bF[nh][n_][0], acc[(mh)*4+i_][(nh)*2+n_]);  \
        acc[(mh)*4+i_][(nh)*2+n_] =                                       \
            mfma16(aF[i_][1], bF[nh][n_][1], acc[(mh)*4+i_][(nh)*2+n_]);  \
      } } }

#define PH_ENTER()                                                        \
    __builtin_amdgcn_s_barrier();                                         \
    asm volatile("s_waitcnt lgkmcnt(0)" ::: "memory");                    \
    __builtin_amdgcn_sched_barrier(0);                                    \
    __builtin_amdgcn_s_setprio(1)

#define PH_EXIT() __builtin_amdgcn_s_setprio(0)

#define EIGHT_PHASE_LOOP()                                                \
    stA(0, 0, 0); stA(0, 1, 0); stB(0, 0, 0); stB(0, 1, 0);               \
    stA(1, 0, 64);                                                        \
    asm volatile("s_waitcnt vmcnt(2)" ::: "memory");                      \
    __builtin_amdgcn_s_barrier();                                         \
    __builtin_amdgcn_sched_barrier(0);                                    \
    for (int j = 0; j < 8; ++j) {                                         \
        const int k1 = (2 * j + 1) * 64;                                  \
        const int k2 = (2 * j + 2) * 64;                                  \
        const int k3 = (2 * j + 3) * 64;                                  \
        const bool more = (j < 7);                                        \
        RD_A(0, 0); RD_B(0, 0);                                           \
        stA(1, 1, k1);                                                    \
        PH_ENTER(); DO_MFMA(0, 0); PH_EXIT();                             \
        __builtin_amdgcn_s_barrier();                                     \
        RD_B(0, 1);                                                       \
        stB(1, 0, k1);                                                    \
        PH_ENTER(); DO_MFMA(0, 1); PH_EXIT();                             \
        __builtin_amdgcn_s_barrier();                                     \
        RD_A(0, 1);                                                       \
        stB(1, 1, k1);                                                    \
        PH_ENTER(); DO_MFMA(1, 1); PH_EXIT();                             \
        __builtin_amdgcn_s_barrier();                                     \
        if (more) stA(0, 0, k2);                                          \
        PH_ENTER(); DO_MFMA(1, 0); PH_EXIT();                             \
        if (more) { asm volatile("s_waitcnt vmcnt(2)" ::: "memory"); }    \
        else      { asm volatile("s_waitcnt vmcnt(0)" ::: "memory"); }    \
        __builtin_amdgcn_s_barrier();                                     \
        RD_A(1, 0); RD_B(1, 0);                                           \
        if (more) stA(0, 1, k2);                                          \
        PH_ENTER(); DO_MFMA(0, 0); PH_EXIT();                             \
        __builtin_amdgcn_s_barrier();                                     \
        RD_B(1, 1);                                                       \
        if (more) stB(0, 0, k2);                                          \
        PH_ENTER(); DO_MFMA(0, 1); PH_EXIT();                             \
        __builtin_amdgcn_s_barrier();                                     \
        RD_A(1, 1);                                                       \
        if (more) stB(0, 1, k2);                                          \
        PH_ENTER(); DO_MFMA(1, 1); PH_EXIT();                             \
        __builtin_amdgcn_s_barrier();                                     \
        if (more) stA(1, 0, k3);                                          \
        PH_ENTER(); DO_MFMA(1, 0); PH_EXIT();                             \
        if (more) {                                                       \
            asm volatile("s_waitcnt vmcnt(2)" ::: "memory");              \
            __builtin_amdgcn_s_barrier();                                 \
        }                                                                 \
    }

// ============================================================
// Fused SwiGLU GEMM — 8-phase 256^2, 32-row-interleaved B (R20-PROVEN)
// ============================================================
__global__ __launch_bounds__(512, 2) void mgemm_glu(
    const unsigned short* __restrict__ B1p,
    const unsigned short* __restrict__ B2p,
    const unsigned short* __restrict__ A,
    const float* __restrict__ bias1,
    const float* __restrict__ bias2,
    unsigned short* __restrict__ C, int ldc)
{
    __shared__ __align__(16) unsigned short As[2][256 * 64];
    __shared__ __align__(16) unsigned short Bs[2][256 * 64];

    const int tid  = threadIdx.x;
    const int lane = tid & 63;
    const int wave = tid >> 6;          // 0..7
    const int l16  = lane & 15;
    const int quad = lane >> 4;
    const int wr   = wave >> 2;         // M half (0..1)
    const int wc   = wave & 3;          // N quarter (0..3)
    const int bn = blockIdx.x, bm = blockIdx.y;
    const int K = CDIM;

    const unsigned short* Ag = A + (size_t)(bm * 256) * K;

    const int srow  = lane >> 3;
    const int sgcol = ((lane & 7) ^ srow) * 8;

    auto stA = [&](int buf, int half, int kt) {
        #pragma unroll
        for (int s = 0; s < 2; ++s) {
            const int rbase = half * 128 + (wave * 2 + s) * 8;
            gld16(&As[buf][rbase * 64],
                  Ag + (size_t)(rbase + srow) * K + kt + sgcol);
        }
    };
    // interleaved B: LDS row rho -> q=rho>>6, r6=rho&63;
    // r6<32 -> W1 row bn*128+q*32+r6 ; else W2 row bn*128+q*32+(r6-32)
    auto stB = [&](int buf, int half, int kt) {
        #pragma unroll
        for (int s = 0; s < 2; ++s) {
            const int rbase = half * 128 + (wave * 2 + s) * 8;
            const int q = rbase >> 6, r6 = rbase & 63;
            const unsigned short* src = (r6 < 32)
                ? B1p + (size_t)(bn * 128 + q * 32 + r6) * K
                : B2p + (size_t)(bn * 128 + q * 32 + (r6 - 32)) * K;
            gld16(&Bs[buf][rbase * 64],
                  src + (size_t)srow * K + kt + sgcol);
        }
    };

    const int e0 = ((quad)     ^ (l16 & 7)) * 8;
    const int e1 = ((quad + 4) ^ (l16 & 7)) * 8;
    const int arow = wr * 128 + l16;
    const int brow = wc * 64 + l16;

    floatx4 acc[8][4] = {};
    bf16x8 aF[4][2];
    bf16x8 bF[2][2][2];

    EIGHT_PHASE_LOOP();

    // epilogue: intra-wave GLU combine, fast silu
    #pragma unroll
    for (int nt = 0; nt < 2; ++nt) {
        const int gcol = bn * 128 + wc * 32 + nt * 16 + l16;
        const float b1 = bias1[gcol];
        const float b2 = bias2[gcol];
        #pragma unroll
        for (int m = 0; m < 8; ++m) {
            #pragma unroll
            for (int r = 0; r < 4; ++r) {
                const int grow = bm * 256 + wr * 128 + m * 16 + quad * 4 + r;
                const float x1 = acc[m][nt][r] + b1;
                const float x2 = acc[m][nt + 2][r] + b2;
                const float e = fexp2(x1 * -1.44269504088896f);
                const float v = x1 * frcp(1.0f + e) * x2;
                C[(size_t)grow * ldc + gcol] = f2bf(v);
            }
        }
    }
}

// ============================================================
// QKV GEMM — 8-phase 256^2 (R19-PROVEN, unchanged)
// ============================================================
__global__ __launch_bounds__(512, 2) void mgemm_qkv(
    const unsigned short* __restrict__ A,
    const unsigned short* __restrict__ B,
    const float* __restrict__ tab,
    unsigned short* __restrict__ Qb,
    unsigned short* __restrict__ Kb,
    unsigned short* __restrict__ Vtb)
{
    __shared__ __align__(16) unsigned short As[2][256 * 64];
    __shared__ __align__(16) unsigned short Bs[2][256 * 64];

    const int tid  = threadIdx.x;
    const int lane = tid & 63;
    const int wave = tid >> 6;          // 0..7
    const int l16  = lane & 15;
    const int quad = lane >> 4;
    const int wr   = wave >> 2;         // M half (0..1)
    const int wc   = wave & 3;          // N quarter (0..3)
    const int bn = blockIdx.x, bm = blockIdx.y;
    const int K = CDIM;

    const unsigned short* Ag = A + (size_t)(bm * 256) * K;
    const unsigned short* Bg = B + (size_t)(bn * 256) * K;

    const int srow  = lane >> 3;
    const int sgcol = ((lane & 7) ^ srow) * 8;

    auto stA = [&](int buf, int half, int kt) {
        #pragma unroll
        for (int s = 0; s < 2; ++s) {
            const int rbase = half * 128 + (wave * 2 + s) * 8;
            gld16(&As[buf][rbase * 64],
                  Ag + (size_t)(rbase + srow) * K + kt + sgcol);
        }
    };
    auto stB = [&](int buf, int half, int kt) {
        #pragma unroll
        for (int s = 0; s < 2; ++s) {
            const int rbase = half * 128 + (wave * 2 + s) * 8;
            gld16(&Bs[buf][rbase * 64],
                  Bg + (size_t)(rbase + srow) * K + kt + sgcol);
        }
    };

    const int e0 = ((quad)     ^ (l16 & 7)) * 8;
    const int e1 = ((quad + 4) ^ (l16 & 7)) * 8;
    const int arow = wr * 128 + l16;
    const int brow = wc * 64 + l16;

    floatx4 acc[8][4] = {};
    bf16x8 aF[4][2];
    bf16x8 bF[2][2][2];

    EIGHT_PHASE_LOOP();

    // ---- epilogues ----
    const int part = bn >> 2;           // 0=q 1=k 2=v (256-col blocks)

    if (part == 2) {
        // V: transpose via LDS (As dead) -> Vtb [bh][d][n], 32B stores
        unsigned short* T = &As[0][0];  // [2][256][16] ushort = 16 KB
        #pragma unroll
        for (int m = 0; m < 8; ++m) {
            __syncthreads();
            #pragma unroll
            for (int n = 0; n < 4; ++n) {
                ushort4 pk;
                pk.x = f2bf(acc[m][n][0]); pk.y = f2bf(acc[m][n][1]);
                pk.z = f2bf(acc[m][n][2]); pk.w = f2bf(acc[m][n][3]);
                *(ushort4*)&T[(wr * 256 + wc * 64 + n * 16 + l16) * 16 + quad * 4] = pk;
            }
            __syncthreads();
            // 512 threads: wr2 = tid>>8, col = tid&255; 32B along n
            const int wr2 = tid >> 8, col = tid & 255;
            const int grow0 = bm * 256 + wr2 * 128 + m * 16;
            const int b = grow0 >> 11, n0 = grow0 & 2047;
            const int h2 = (bn & 3) * 4 + (col >> 6);
            const int d  = col & 63;
            unsigned short* dst = Vtb +
                ((size_t)(b * NH + h2) * 64 + d) * 2048 + n0;
            const int tb = (wr2 * 256 + col) * 16;
            *(uint4*)dst       = *(const uint4*)&T[tb];
            *(uint4*)(dst + 8) = *(const uint4*)&T[tb + 8];
        }
    } else {
        // q/k: fp32 RoPE; q scaled by 0.125*log2e (exp2 softmax)
        const float qscale = (part == 0) ? 0.125f * 1.44269504088896f : 1.0f;
        const int h = (bn & 3) * 4 + wc;
        unsigned short* qk = (part == 0) ? Qb : Kb;
        #pragma unroll
        for (int m = 0; m < 8; ++m) {
            #pragma unroll
            for (int r = 0; r < 4; ++r) {
                const int grow = bm * 256 + wr * 128 + m * 16 + quad * 4 + r;
                const int b = grow >> 11, n = grow & 2047;
                unsigned short* dst = qk + ((size_t)(b * NH + h) * 2048 + n) * 64;
                #pragma unroll
                for (int nt = 0; nt < 2; ++nt) {
                    const int i = nt * 16 + l16;          // 0..31
                    const float c  = tab[(n * 32 + i) * 2];
                    const float sn = tab[(n * 32 + i) * 2 + 1];
                    const float x1  = acc[m][nt][r];
                    const float x2v = acc[m][nt + 2][r];
                    dst[i]      = f2bf((x1 * c - x2v * sn) * qscale);
                    dst[i + 32] = f2bf((x2v * c + x1 * sn) * qscale);
                }
            }
        }
    }
}

// ============================================================
// MFMA flash attention v5b: v4 + lgkm-only tile-ready barrier (the
// T14 prefetch now spans kt's compute; vmcnt drain deferred to the
// loop-top __syncthreads, after compute). NO setprio (m190: negative
// on barrier-synced lockstep waves — confirmed by R21's regression).
// ============================================================
__global__ __launch_bounds__(256) void attn_mfma(
    const unsigned short* __restrict__ Qb,
    const unsigned short* __restrict__ Kb,
    const unsigned short* __restrict__ Vtb,
    unsigned short* __restrict__ Ob)
{
    const int bh = blockIdx.x;        // 0..63  (x-major: same-bh -> same XCD)
    const int qt = blockIdx.y;        // 0..15
    const int tid = threadIdx.x;
    const int lane = tid & 63, wave = tid >> 6;
    const int r32 = lane & 31, hi = lane >> 5;
    const int qrow = wave * 32 + r32; // this lane's query row in LDS

    __shared__ unsigned short QP[128][72];  // Q staging (held all iters)
    __shared__ unsigned short Ks[64][72];   // K tile [key][dim]
    __shared__ unsigned short Vs[64][72];   // V^T tile [dim][key]

    const unsigned short* Qg = Qb + ((size_t)bh * 2048 + qt * 128) * 64;
    const unsigned short* Kg = Kb + (size_t)bh * 2048 * 64;
    const unsigned short* Vg = Vtb + (size_t)bh * 64 * 2048;

    // stage Q tile 128x64
    #pragma unroll
    for (int rep = 0; rep < 4; ++rep) {
        const int c = tid + rep * 256;
        const int r = c >> 3, d0 = (c & 7) * 8;
        *(uint4*)&QP[r][d0] = *(const uint4*)(Qg + (size_t)r * 64 + d0);
    }

    // K/V staging slots for this thread (2 b128 each per tile)
    const int c0 = tid, c1 = tid + 256;
    const int kr0 = c0 >> 3, kd0 = (c0 & 7) * 8;
    const int kr1 = c1 >> 3, kd1 = (c1 & 7) * 8;

    // T14 prefetch tile 0 into regs
    uint4 ka0 = *(const uint4*)(Kg + (size_t)kr0 * 64 + kd0);
    uint4 ka1 = *(const uint4*)(Kg + (size_t)kr1 * 64 + kd1);
    uint4 va0 = *(const uint4*)(Vg + (size_t)kr0 * 2048 + kd0);
    uint4 va1 = *(const uint4*)(Vg + (size_t)kr1 * 2048 + kd1);

    __syncthreads();   // Q tile ready

    // Q B-frags (rows = wave's 32 queries), held for all iterations
    bf16x8 bq[4];
    #pragma unroll
    for (int f = 0; f < 4; ++f)
        bq[f] = *(const bf16x8*)&QP[qrow][f * 16 + hi * 8];

    floatx16 o0 = {}, o1 = {};      // O^T[d][q]: d-tiles 0..31 / 32..63
    float l_acc = 0.0f;

    for (int kt = 0; kt < 32; ++kt) {
        __syncthreads();   // prev tile's reads done; drains prefetch (needed
                           // anyway by the ds_writes below)
        *(uint4*)&Ks[kr0][kd0] = ka0;
        *(uint4*)&Ks[kr1][kd1] = ka1;
        *(uint4*)&Vs[kr0][kd0] = va0;
        *(uint4*)&Vs[kr1][kd1] = va1;
        if (kt + 1 < 32) {           // T14: issue next-tile loads now;
            const size_t nb = (size_t)(kt + 1) * 64;     // they stay in flight
            ka0 = *(const uint4*)(Kg + (nb + kr0) * 64 + kd0);   // across kt's
            ka1 = *(const uint4*)(Kg + (nb + kr1) * 64 + kd1);   // compute (no
            va0 = *(const uint4*)(Vg + (size_t)kr0 * 2048 + nb + kd0); // vmcnt
            va1 = *(const uint4*)(Vg + (size_t)kr1 * 2048 + nb + kd1); // drain)
        }
        // tile-ready: ds_writes visible; do NOT drain vmcnt (prefetch flies)
        asm volatile("s_waitcnt lgkmcnt(0)" ::: "memory");
        __builtin_amdgcn_s_barrier();
        __builtin_amdgcn_sched_barrier(0);

        // ---- per 32-key subtile: S^T -> exp2 -> in-reg P -> PV ----
        #pragma unroll
        for (int t = 0; t < 2; ++t) {
            floatx16 s = {};
            #pragma unroll
            for (int f = 0; f < 4; ++f) {
                const bf16x8 ak = *(const bf16x8*)&Ks[t * 32 + r32][f * 16 + hi * 8];
                s = mfma32(ak, bq[f], s);
            }
            // p = exp2(s); rowsum
            float p[16];
            float rs = 0.0f;
            #pragma unroll
            for (int g = 0; g < 16; ++g) { p[g] = fexp2(s[g]); rs += p[g]; }
            l_acc += rs;
            // pack to bf16 words and swap halves across hi
            u32 w0 = cvtpk(p[0], p[1]),   w2 = cvtpk(p[4], p[5]);
            u32 w1 = cvtpk(p[2], p[3]),   w3 = cvtpk(p[6], p[7]);
            u32 w4 = cvtpk(p[8], p[9]),   w6 = cvtpk(p[12], p[13]);
            u32 w5 = cvtpk(p[10], p[11]), w7 = cvtpk(p[14], p[15]);
            asm("v_permlane32_swap_b32 %0, %1" : "+v"(w0), "+v"(w2));
            asm("v_permlane32_swap_b32 %0, %1" : "+v"(w1), "+v"(w3));
            asm("v_permlane32_swap_b32 %0, %1" : "+v"(w4), "+v"(w6));
            asm("v_permlane32_swap_b32 %0, %1" : "+v"(w5), "+v"(w7));
            uint4 u0; u0.x = w0; u0.y = w1; u0.z = w2; u0.w = w3;
            uint4 u1; u1.x = w4; u1.y = w5; u1.z = w6; u1.w = w7;
            const bf16x8 bp0 = __builtin_bit_cast(bf16x8, u0);  // keys t*32 + slot0
            const bf16x8 bp1 = __builtin_bit_cast(bf16x8, u1);  // keys t*32 + slot1
            // PV for this subtile's two 16-key slots (f = 2t, 2t+1)
            {
                const int f0 = 2 * t, f1 = 2 * t + 1;
                const bf16x8 av00 = *(const bf16x8*)&Vs[r32][f0 * 16 + hi * 8];
                const bf16x8 av01 = *(const bf16x8*)&Vs[32 + r32][f0 * 16 + hi * 8];
                o0 = mfma32(av00, bp0, o0);
                o1 = mfma32(av01, bp0, o1);
                const bf16x8 av10 = *(const bf16x8*)&Vs[r32][f1 * 16 + hi * 8];
                const bf16x8 av11 = *(const bf16x8*)&Vs[32 + r32][f1 * 16 + hi * 8];
                o0 = mfma32(av10, bp1, o0);
                o1 = mfma32(av11, bp1, o1);
            }
        }
    }

    // epilogue: lane's query = wave*32 + r32; lanes l/l+32 hold disjoint key
    // halves of the same query -> one shfl to complete l.
    const float l_tot = l_acc + __shfl_xor(l_acc, 32);
    const float inv = 1.0f / l_tot;
    const int b = bh >> 4, h = bh & 15;
    unsigned short* orow = Ob +
        (size_t)(b * SEQ + qt * 128 + qrow) * CDIM + h * 64;
    #pragma unroll
    for (int u = 0; u < 2; ++u) {
        const floatx16 ov = u ? o1 : o0;
        #pragma unroll
        for (int g = 0; g < 4; ++g) {
            ushort4 pk;
            pk.x = f2bf(ov[4 * g + 0] * inv); pk.y = f2bf(ov[4 * g + 1] * inv);
            pk.z = f2bf(ov[4 * g + 2] * inv); pk.w = f2bf(ov[4 * g + 3] * inv);
            // d = u*32 + 8g + 4*hi + (0..3)
            *(ushort4*)(orow + u * 32 + 8 * g + 4 * hi) = pk;
        }
    }
}

// ============================================================
// One-shot fp32 -> bf16 for all six tensors (block-uniform segments);
// RoPE table (fp64 angles)
// ============================================================
__global__ __launch_bounds__(256) void cvt_all(
    const float* __restrict__ x,    const float* __restrict__ qkv,
    const float* __restrict__ proj, const float* __restrict__ w1,
    const float* __restrict__ w2,   const float* __restrict__ w3,
    unsigned short* __restrict__ xb,    unsigned short* __restrict__ qkvb,
    unsigned short* __restrict__ projb, unsigned short* __restrict__ w1b,
    unsigned short* __restrict__ w2b,   unsigned short* __restrict__ w3b)
{
    const size_t i = ((size_t)blockIdx.x * 256 + threadIdx.x) * 4;
    const float* src; unsigned short* dst; size_t off;
    if      (i <  8388608) { src = x;    dst = xb;    off = 0; }
    else if (i < 11534336) { src = qkv;  dst = qkvb;  off = 8388608; }
    else if (i < 12582912) { src = proj; dst = projb; off = 11534336; }
    else if (i < 14680064) { src = w1;   dst = w1b;   off = 12582912; }
    else if (i < 16777216) { src = w2;   dst = w2b;   off = 14680064; }
    else                   { src = w3;   dst = w3b;   off = 16777216; }
    const size_t j = i - off;
    const float4 f = *(const float4*)(src + j);
    ushort4 o; o.x = f2bf(f.x); o.y = f2bf(f.y); o.z = f2bf(f.z); o.w = f2bf(f.w);
    *(ushort4*)(dst + j) = o;
}

__global__ __launch_bounds__(256) void rope_table(float* __restrict__ tab)
{
    const int idx = blockIdx.x * 256 + threadIdx.x;   // < 65536
    const int i = idx & 31, n = idx >> 5;
    const double f = (double)n * pow(10000.0, -(double)(2 * i) / 64.0);
    tab[idx * 2]     = (float)cos(f);
    tab[idx * 2 + 1] = (float)sin(f);
}

// ============================================================
// kernel_launch
// ============================================================
extern "C" void kernel_launch(void* const* d_in, const int* in_sizes, int n_in,
                              void* d_out, int out_size, void* d_ws, size_t ws_size,
                              hipStream_t stream)
{
    const float* x      = (const float*)d_in[0];
    const float* qkv_w  = (const float*)d_in[1];
    const float* proj_w = (const float*)d_in[2];
    const float* proj_b = (const float*)d_in[3];
    const float* w1_w   = (const float*)d_in[4];
    const float* w1_b   = (const float*)d_in[5];
    const float* w2_w   = (const float*)d_in[6];
    const float* w2_b   = (const float*)d_in[7];
    const float* w3_w   = (const float*)d_in[8];
    const float* w3_b   = (const float*)d_in[9];
    float* out = (float*)d_out;

    char* ws = (char*)d_ws;
    unsigned short* Qb    = (unsigned short*)(ws);              // [0,16M)
    unsigned short* Kb    = (unsigned short*)(ws + 16777216);   // [16,32M)
    unsigned short* Vtb   = (unsigned short*)(ws + 33554432);   // [32,48M)
    unsigned short* Ob    = (unsigned short*)(ws + 50331648);   // [48,64M)
    unsigned short* out1b = (unsigned short*)(ws + 67108864);   // [64,80M)
    unsigned short* w1b   = (unsigned short*)(ws + 83886080);   // [80,84M)
    unsigned short* w2b   = (unsigned short*)(ws + 88080384);   // [84,88M)
    unsigned short* w3b   = (unsigned short*)(ws + 92274688);   // [88,92M)
    unsigned short* projb = (unsigned short*)(ws + 96468992);   // [92,94M)
    unsigned short* xb    = (unsigned short*)(ws + 98566144);   // [94,110M)
    unsigned short* wqkvb = (unsigned short*)(ws + 115343360);  // [110,116M)
    float*          tab   = (float*)(ws + 121634816);           // [116,116.5M)
    unsigned short* hid   = (unsigned short*)(ws);              // [0,32M)

    const dim3 blk(256);

    // all fp32->bf16 conversions in one dispatch (18874368 elems / 1024)
    cvt_all<<<dim3(18432), blk, 0, stream>>>(
        x, qkv_w, proj_w, w1_w, w2_w, w3_w,
        xb, wqkvb, projb, w1b, w2b, w3b);
    rope_table<<<dim3(256), blk, 0, stream>>>(tab);

    // 1) QKV GEMM (8-phase 256^2) + fused rope/scale + V transpose
    mgemm_qkv<<<dim3(12, 32), dim3(512), 0, stream>>>(xb, wqkvb, tab, Qb, Kb, Vtb);
    // 2) MFMA flash attention; grid (bh, qt) -> same-bh blocks co-XCD
    attn_mfma<<<dim3(BATCH * NH, SEQ / 128), blk, 0, stream>>>(Qb, Kb, Vtb, Ob);
    // 3) out1b = Ob @ projb^T + proj_b (bf16)  [2-phase, R20-proven]
    mgemm<1, true><<<dim3(8, 64), blk, 0, stream>>>(
        Ob, projb, proj_b, out1b, CDIM, CDIM);
    // 4) hid = silu(out1b@w1^T + b1) * (out1b@w2^T + b2)  [8-phase fused]
    mgemm_glu<<<dim3(16, 32), dim3(512), 0, stream>>>(
        w1b, w2b, out1b, w1_b, w2_b, hid, 2048);
    // 5) out = hid @ w3b^T + w3_b (fp32 -> d_out)  [2-phase, R20-proven]
    mgemm<0, true><<<dim3(8, 64), blk, 0, stream>>>(
        hid, w3b, w3_b, out, CDIM, 2048);
}